// Round 1
// 95.354 us; speedup vs baseline: 1.0010x; 1.0010x over previous
//
#include <hip/hip_runtime.h>

#define HH 32          // LSTM size
#define TT 20          // total steps (14 kernel + 3 down + 3 up)

typedef float v2f __attribute__((ext_vector_type(2)));

#define LOG2E  1.4426950408889634f
#define LN2    0.6931471805599453f

__device__ __forceinline__ float fsig(float x) {
    return __builtin_amdgcn_rcpf(1.0f + __builtin_amdgcn_exp2f(-x * LOG2E));
}
__device__ __forceinline__ float ftanh(float x) {
    return 1.0f - 2.0f * __builtin_amdgcn_rcpf(1.0f + __builtin_amdgcn_exp2f(x * (2.0f * LOG2E)));
}

// R8: barrier-free single-wave variant.
// One block, ONE wave => wave64 lockstep + in-order DS pipe + compiler
// lgkmcnt insertion already order every LDS write->read (h_s, emb_s, Gv,
// gum_s). __syncthreads() was emitting a full
// `s_waitcnt vmcnt(0) expcnt(0) lgkmcnt(0)` + s_barrier PER STEP, which
// serialized the step's sample global_store ack (~200-500 cyc L2 round
// trip) into the 20-step dependency chain. Changes vs R7 (94.6 us):
//   (1) all __syncthreads removed;
//   (2) per-step out[2+step] store replaced by a per-lane register capture
//       (lane t keeps step t-2's sample) + ONE coalesced 22-lane store at
//       kernel end -> zero outstanding vmem in the loop.
// Everything else (resident whh 128 VGPR + hk 32, G-precompute in LDS,
// lane-local gates, 8-shfl logit gather, pairwise strict-> argmax tree)
// is unchanged from the session-best kernel.
__global__ __launch_bounds__(64, 1) void controller_kernel(
    const float* __restrict__ w_ih,      // [128,32]
    const float* __restrict__ w_hh,      // [128,32]
    const float* __restrict__ b_ih,      // [128]
    const float* __restrict__ b_hh,      // [128]
    const float* __restrict__ g_emb,     // [1,32]
    const float* __restrict__ emb_kernel,// [8,32]
    const float* __restrict__ emb_down,  // [3,32]
    const float* __restrict__ emb_up,    // [3,32]
    const float* __restrict__ w_kernel,  // [8,32]
    const float* __restrict__ w_down,    // [3,32]
    const float* __restrict__ w_up,      // [3,32]
    const float* __restrict__ noise,     // [20,8]
    float* __restrict__ out)             // [22] = stats[2] ++ samples[20]
{
    const int t   = threadIdx.x;   // 0..63
    const int q   = t & 31;        // gate-set (lanes 32..63 duplicate the cell)
    const int cls = t & 7;         // logit class this lane owns

    __shared__ __align__(16) float emb_s[15 * 32];    // 0..7 kern, 8..10 down, 11..13 up, 14 g_emb
    __shared__ __align__(16) float Gv[15 * 32 * 4];   // [e][q][4] = (i,f,g,o) precomp
    __shared__ __align__(16) float h_s[32];
    __shared__ __align__(16) float gum_s[TT * 8];
    __shared__ __align__(16) float head_pre[2 * 64 * 4]; // tail heads (down,up) per-lane float4

    // ---- stage embeddings, gumbel noise, tail-head prearrange ----
    for (int i = t; i < 15 * 32; i += 64) {
        const int r = i >> 5, j = i & 31;
        float v;
        if (r < 8)       v = emb_kernel[i];
        else if (r < 11) v = emb_down[i - 8 * 32];
        else if (r < 14) v = emb_up[i - 11 * 32];
        else             v = g_emb[j];
        emb_s[i] = v;
    }
    for (int i = t; i < TT * 8; i += 64) {
        const float u = noise[i];
        gum_s[i] = -logf(-logf(u * (1.0f - 1e-6f) + 1e-7f));   // off critical path
    }
#pragma unroll
    for (int bi = 0; bi < 2; ++bi) {                 // 0=down, 1=up
        float4 v = make_float4(0.f, 0.f, 0.f, 0.f);
        if (cls < 3) {
            const float* W = (bi == 0) ? w_down : w_up;
            v = *(const float4*)(W + cls * 32 + (t >> 3) * 4);
        }
        *(float4*)(head_pre + (bi * 64 + t) * 4) = v;
    }

    float bias[4];
#pragma unroll
    for (int g = 0; g < 4; ++g) bias[g] = b_ih[q + 32 * g] + b_hh[q + 32 * g];

    // ---- G precompute into LDS; half-waves split the 15 embeddings ----
    // (no barrier: single-wave lockstep, emb_s RAW ordered by the DS pipe +
    //  compiler lgkmcnt)
    {
        v2f wih[64];                                  // transient; dies before whh loads
#pragma unroll
        for (int g = 0; g < 4; ++g) {
            const float4* p = (const float4*)(w_ih + (q + 32 * g) * HH);
#pragma unroll
            for (int k8 = 0; k8 < 8; ++k8) {
                const float4 a = p[k8];
                wih[g * 16 + 2 * k8]     = (v2f){a.x, a.y};
                wih[g * 16 + 2 * k8 + 1] = (v2f){a.z, a.w};
            }
        }
        const int e0 = (t < 32) ? 0 : 8;
        const int e1 = (t < 32) ? 8 : 15;
        for (int e = e0; e < e1; ++e) {
            const float4* ep = (const float4*)(emb_s + e * 32);
            v2f g0 = {0.f,0.f}, g1 = {0.f,0.f}, g2 = {0.f,0.f}, g3 = {0.f,0.f};
#pragma unroll
            for (int k8 = 0; k8 < 8; ++k8) {
                const float4 a = ep[k8];
                const v2f x0 = {a.x, a.y}, x1 = {a.z, a.w};
                g0 += wih[2*k8]    * x0;  g0 += wih[2*k8+1]    * x1;
                g1 += wih[16+2*k8] * x0;  g1 += wih[16+2*k8+1] * x1;
                g2 += wih[32+2*k8] * x0;  g2 += wih[32+2*k8+1] * x1;
                g3 += wih[48+2*k8] * x0;  g3 += wih[48+2*k8+1] * x1;
            }
            *(float4*)(Gv + (e * 32 + q) * 4) =
                make_float4(bias[0] + g0.x + g0.y, bias[1] + g1.x + g1.y,
                            bias[2] + g2.x + g2.y, bias[3] + g3.x + g3.y);
        }
    }
    __builtin_amdgcn_sched_barrier(0);   // keep whh/hk loads out of the G phase

    // ---- resident weights: whh (128 VGPRs) + kernel head hk (32 VGPRs) ----
    v2f whh[64];
#pragma unroll
    for (int g = 0; g < 4; ++g) {
        const float4* p = (const float4*)(w_hh + (q + 32 * g) * HH);
#pragma unroll
        for (int k8 = 0; k8 < 8; ++k8) {
            const float4 a = p[k8];
            whh[g * 16 + 2 * k8]     = (v2f){a.x, a.y};
            whh[g * 16 + 2 * k8 + 1] = (v2f){a.z, a.w};
        }
    }
    v2f hk[16];
#pragma unroll
    for (int k8 = 0; k8 < 8; ++k8) {
        const float4 a = ((const float4*)(w_kernel + cls * 32))[k8];
        hk[2*k8] = (v2f){a.x, a.y}; hk[2*k8+1] = (v2f){a.z, a.w};
    }

    v2f hreg[16];
#pragma unroll
    for (int k = 0; k < 16; ++k) hreg[k] = (v2f){0.f, 0.f};
    float  c_reg = 0.0f;
    float4 G4 = *(const float4*)(Gv + (14 * 32 + q) * 4);   // first x = g_emb
    float  lp_sum = 0.0f, ent_sum = 0.0f;
    float  my_idx = 0.0f;          // lane t (t>=2) keeps step t-2's sample

    for (int step = 0; step < TT; ++step) {
        // ---- A: gates = G4 + W_hh @ h (4 rows lane-local) ----
        v2f ai = {0.f,0.f}, af = {0.f,0.f}, ag = {0.f,0.f}, ao = {0.f,0.f};
#pragma unroll
        for (int k = 0; k < 16; ++k) {
            ai += whh[k]      * hreg[k];
            af += whh[16 + k] * hreg[k];
            ag += whh[32 + k] * hreg[k];
            ao += whh[48 + k] * hreg[k];
        }
        const float gi_ = G4.x + ai.x + ai.y;
        const float gf_ = G4.y + af.x + af.y;
        const float gg_ = G4.z + ag.x + ag.y;
        const float go_ = G4.w + ao.x + ao.y;

        // ---- B: cell (both halves duplicate; lanes 0..31 write h) ----
        const float ig = fsig(gi_), fg = fsig(gf_), gv = ftanh(gg_), og = fsig(go_);
        c_reg = fg * c_reg + ig * gv;
        const float hn = og * ftanh(c_reg);
        if (t < 32) h_s[t] = hn;
        // no __syncthreads: same-object LDS RAW is ordered by the in-order
        // DS pipe; compiler inserts the lgkmcnt wait before the reads below.

        // ---- broadcast h into regs (feeds logit dot and next step's gates) ----
#pragma unroll
        for (int k8 = 0; k8 < 8; ++k8) {
            const float4 hv = ((const float4*)h_s)[k8];
            hreg[2*k8] = (v2f){hv.x, hv.y}; hreg[2*k8+1] = (v2f){hv.z, hv.w};
        }

        // ---- C: logit for class cls ----
        float l;
        if (step < 14) {                       // kernel head: resident, full 32-dot
            v2f s0 = {0.f,0.f}, s1 = {0.f,0.f};
#pragma unroll
            for (int k = 0; k < 16; k += 2) { s0 += hk[k]*hreg[k]; s1 += hk[k+1]*hreg[k+1]; }
            l = (s0.x + s0.y) + (s1.x + s1.y);  // n=8: no masking
        } else {                               // down/up: LDS partial + 3 xor shuffles
            const int bi = (step < 17) ? 0 : 1;
            const float4 hp = *(const float4*)(head_pre + (bi * 64 + t) * 4);
            const float4 hv = ((const float4*)h_s)[t >> 3];
            float p = hp.x*hv.x + hp.y*hv.y + hp.z*hv.z + hp.w*hv.w;
            p += __shfl_xor(p, 8);
            p += __shfl_xor(p, 16);
            p += __shfl_xor(p, 32);
            l = (cls < 3) ? p : -1e9f;
        }

        // ---- D: gather 8 logits; lane-local stats + pairwise argmax tree ----
        float lv[8];
#pragma unroll
        for (int k = 0; k < 8; ++k) lv[k] = __shfl(l, k);

        float S = 0.0f, Tm = 0.0f;
#pragma unroll
        for (int k = 0; k < 8; ++k) {
            const float e = __builtin_amdgcn_exp2f(lv[k] * LOG2E);  // masked -> 0
            S += e; Tm += e * lv[k];
        }
        const float4 gA = ((const float4*)(gum_s + step * 8))[0];
        const float4 gB = ((const float4*)(gum_s + step * 8))[1];
        const float v0 = lv[0]+gA.x, v1 = lv[1]+gA.y, v2 = lv[2]+gA.z, v3 = lv[3]+gA.w;
        const float v4 = lv[4]+gB.x, v5 = lv[5]+gB.y, v6 = lv[6]+gB.z, v7 = lv[7]+gB.w;
        // strict > at every level keeps the FIRST max index (jnp.argmax rule)
        const bool ta = v1 > v0;  const float va = ta?v1:v0;  const int ia = ta?1:0;  const float la = ta?lv[1]:lv[0];
        const bool tb = v3 > v2;  const float vb = tb?v3:v2;  const int ib = tb?3:2;  const float lb = tb?lv[3]:lv[2];
        const bool tc = v5 > v4;  const float vc = tc?v5:v4;  const int ic = tc?5:4;  const float lc = tc?lv[5]:lv[4];
        const bool td = v7 > v6;  const float vd = td?v7:v6;  const int id_= td?7:6;  const float ld = td?lv[7]:lv[6];
        const bool tab = vb > va; const float vab = tab?vb:va; const int iab = tab?ib:ia; const float lab = tab?lb:la;
        const bool tcd = vd > vc; const float vcd = tcd?vd:vc; const int icd = tcd?id_:ic; const float lcd = tcd?ld:lc;
        const bool tf  = vcd > vab;
        const int   idx = tf ? icd : iab;
        const float bl  = tf ? lcd : lab;

        const float lse = __builtin_amdgcn_logf(S) * LN2;
        lp_sum  += bl - lse;
        ent_sum += lse - Tm * __builtin_amdgcn_rcpf(S);
        if (t - 2 == step) my_idx = (float)idx;   // register capture, no store

        // ---- E: next G4; table base = CURRENT step (reference semantics) ----
        const int base = (step < 14) ? 0 : ((step < 17) ? 8 : 11);
        G4 = *(const float4*)(Gv + ((base + idx) * 32 + q) * 4);
    }

    // ---- single coalesced 22-lane store: [lp, ent, samples 0..19] ----
    float oval = my_idx;
    if (t == 0) oval = lp_sum;
    if (t == 1) oval = ent_sum;
    if (t < 22) out[t] = oval;
}

extern "C" void kernel_launch(void* const* d_in, const int* in_sizes, int n_in,
                              void* d_out, int out_size, void* d_ws, size_t ws_size,
                              hipStream_t stream) {
    (void)in_sizes; (void)n_in; (void)out_size; (void)d_ws; (void)ws_size;
    const float* w_ih       = (const float*)d_in[0];
    const float* w_hh       = (const float*)d_in[1];
    const float* b_ih       = (const float*)d_in[2];
    const float* b_hh       = (const float*)d_in[3];
    const float* g_emb      = (const float*)d_in[4];
    const float* emb_kernel = (const float*)d_in[5];
    const float* emb_down   = (const float*)d_in[6];
    const float* emb_up     = (const float*)d_in[7];
    const float* w_kernel   = (const float*)d_in[8];
    const float* w_down     = (const float*)d_in[9];
    const float* w_up       = (const float*)d_in[10];
    const float* noise      = (const float*)d_in[11];
    float* out = (float*)d_out;

    hipLaunchKernelGGL(controller_kernel, dim3(1), dim3(64), 0, stream,
                       w_ih, w_hh, b_ih, b_hh, g_emb, emb_kernel, emb_down,
                       emb_up, w_kernel, w_down, w_up, noise, out);
}